// Round 3
// baseline (665.340 us; speedup 1.0000x reference)
//
#include <hip/hip_runtime.h>
#include <math.h>

#define L_SEQ 4096
#define D_HEAD 64
#define M_WIN 128
#define WIN 257              // 2*M+1
#define QB 8                 // query rows per block
#define W 264                // WIN + QB - 1, divisible by 4
#define WF4 66               // W/4
#define SCALE 0.125f         // 1/sqrt(64)

typedef float v4f __attribute__((ext_vector_type(4)));

__global__ __launch_bounds__(256, 8) void win_attn_kernel(
    const float* __restrict__ Q, const float* __restrict__ K,
    const float* __restrict__ V, float* __restrict__ OutO,
    float* __restrict__ OutA)
{
    extern __shared__ float smem[];
    float*  att  = smem;                 // [QB][W]   (f4 row stride 66)
    float*  q_s  = smem + QB * W;        // [QB][68]  padded (f4 row stride 17)
    float4* att4 = (float4*)att;
    float4* q_s4 = (float4*)q_s;

    const int t   = threadIdx.x;
    const int w   = t >> 6;              // wave 0..3
    const int ln  = t & 63;
    const int bid = blockIdx.x;
    const int b   = bid >> 9;            // 512 q-blocks per batch
    const int q0  = (bid & 511) * QB;

    int s0 = q0 - M_WIN;
    if (s0 < 0) s0 = 0;
    if (s0 > L_SEQ - WIN) s0 = L_SEQ - WIN;
    const int wcount = (L_SEQ - s0 < W) ? (L_SEQ - s0) : W;   // valid union cols

    // ---------------- Phase A: stage Q only (padded rows) ----------------
    if (t < QB * 16) {
        const float4* Qg = (const float4*)(Q + ((size_t)(b * L_SEQ + q0)) * D_HEAD);
        int q = t >> 4, c = t & 15;
        q_s4[q * 17 + c] = Qg[t];
    }
    __syncthreads();

    // ---------------- Phase B: scores, 2q x 4col register tile per lane ----
    {
        const float4* Kg = (const float4*)(K + ((size_t)(b * L_SEQ + s0)) * D_HEAD);
        const int qg = ln >> 4;          // 0..3 -> q rows {2qg, 2qg+1}
        const int cg = ln & 15;          // col group
        for (int base = 64 * w; base < W; base += 256) {
            int col0 = base + 4 * cg;
            if (col0 < W) {
                int c0 = (col0 + 0 < wcount) ? col0 + 0 : wcount - 1;
                int c1 = (col0 + 1 < wcount) ? col0 + 1 : wcount - 1;
                int c2 = (col0 + 2 < wcount) ? col0 + 2 : wcount - 1;
                int c3 = (col0 + 3 < wcount) ? col0 + 3 : wcount - 1;
                const float4* kp0 = Kg + (size_t)c0 * 16;
                const float4* kp1 = Kg + (size_t)c1 * 16;
                const float4* kp2 = Kg + (size_t)c2 * 16;
                const float4* kp3 = Kg + (size_t)c3 * 16;
                float4 a0 = {0.f,0.f,0.f,0.f};   // q=2qg,   x..w = cols 0..3
                float4 a1 = {0.f,0.f,0.f,0.f};   // q=2qg+1
                #pragma unroll
                for (int c = 0; c < 16; ++c) {
                    float4 qa = q_s4[(2 * qg)     * 17 + c];
                    float4 qb = q_s4[(2 * qg + 1) * 17 + c];
                    float4 k0 = kp0[c], k1 = kp1[c], k2 = kp2[c], k3 = kp3[c];
                    a0.x += qa.x*k0.x + qa.y*k0.y + qa.z*k0.z + qa.w*k0.w;
                    a0.y += qa.x*k1.x + qa.y*k1.y + qa.z*k1.z + qa.w*k1.w;
                    a0.z += qa.x*k2.x + qa.y*k2.y + qa.z*k2.z + qa.w*k2.w;
                    a0.w += qa.x*k3.x + qa.y*k3.y + qa.z*k3.z + qa.w*k3.w;
                    a1.x += qb.x*k0.x + qb.y*k0.y + qb.z*k0.z + qb.w*k0.w;
                    a1.y += qb.x*k1.x + qb.y*k1.y + qb.z*k1.z + qb.w*k1.w;
                    a1.z += qb.x*k2.x + qb.y*k2.y + qb.z*k2.z + qb.w*k2.w;
                    a1.w += qb.x*k3.x + qb.y*k3.y + qb.z*k3.z + qb.w*k3.w;
                }
                float4 r0, r1;
                r0.x = a0.x*SCALE; r0.y = a0.y*SCALE; r0.z = a0.z*SCALE; r0.w = a0.w*SCALE;
                r1.x = a1.x*SCALE; r1.y = a1.y*SCALE; r1.z = a1.z*SCALE; r1.w = a1.w*SCALE;
                att4[(2 * qg)     * WF4 + (col0 >> 2)] = r0;
                att4[(2 * qg + 1) * WF4 + (col0 >> 2)] = r1;
            }
        }
    }
    __syncthreads();

    // ---------------- Phase C: masked softmax per q row (pre-normalized) ----
    {
        const int q  = t >> 5;            // 0..7
        const int i  = t & 31;
        const int qg = q0 + q;
        int st = qg - M_WIN;
        if (st < 0) st = 0;
        if (st > L_SEQ - WIN) st = L_SEQ - WIN;
        const int lo = st - s0;           // window start within union

        float sv[9];
        float m = -1e30f;
        #pragma unroll
        for (int j = 0; j < 9; ++j) {
            int col = i + 32 * j;
            float s = -1e30f;
            if (col < W) {
                s = att[q * W + col];
                if (col < lo || col >= lo + WIN) s = -1e30f;
            }
            sv[j] = s;
            m = fmaxf(m, s);
        }
        #pragma unroll
        for (int k = 16; k >= 1; k >>= 1) m = fmaxf(m, __shfl_xor(m, k, 32));
        float sum = 0.f;
        #pragma unroll
        for (int j = 0; j < 9; ++j) {
            float e = (sv[j] <= -1e29f) ? 0.f : __expf(sv[j] - m);
            sv[j] = e;
            sum += e;
        }
        #pragma unroll
        for (int k = 16; k >= 1; k >>= 1) sum += __shfl_xor(sum, k, 32);
        const float inv = 1.f / sum;
        #pragma unroll
        for (int j = 0; j < 9; ++j) {
            int col = i + 32 * j;
            if (col < W) att[q * W + col] = sv[j] * inv;   // exact 0 outside window
        }
    }
    __syncthreads();

    // ---------------- Phase D: stream dense attention rows (537 MB) ---------
    if ((s0 & 3) == 0) {
        #pragma unroll 1
        for (int ql = 0; ql < QB; ++ql) {
            v4f* rowp = (v4f*)(OutA + ((size_t)(b * L_SEQ + q0 + ql)) * L_SEQ);
            const v4f* arow = (const v4f*)(att + ql * W);
            #pragma unroll
            for (int jj = 0; jj < 4; ++jj) {
                int f4i = jj * 256 + t;
                int u   = 4 * f4i - s0;
                v4f wv = {0.f,0.f,0.f,0.f};
                if (u >= 0 && u < W) wv = arow[u >> 2];     // aligned b128 read
                __builtin_nontemporal_store(wv, rowp + f4i);
            }
        }
    } else {   // rare top-edge blocks (s0 = 3839)
        #pragma unroll 1
        for (int ql = 0; ql < QB; ++ql) {
            v4f* rowp = (v4f*)(OutA + ((size_t)(b * L_SEQ + q0 + ql)) * L_SEQ);
            const float* arow = att + ql * W;
            #pragma unroll
            for (int jj = 0; jj < 4; ++jj) {
                int f4i = jj * 256 + t;
                int u   = 4 * f4i - s0;
                v4f wv;
                wv.x = (u     >= 0 && u     < W) ? arow[u]     : 0.f;
                wv.y = (u + 1 >= 0 && u + 1 < W) ? arow[u + 1] : 0.f;
                wv.z = (u + 2 >= 0 && u + 2 < W) ? arow[u + 2] : 0.f;
                wv.w = (u + 3 >= 0 && u + 3 < W) ? arow[u + 3] : 0.f;
                __builtin_nontemporal_store(wv, rowp + f4i);
            }
        }
    }

    // ---------------- Phase E: PV; wave w owns q rows {2w, 2w+1} ------------
    {
        const int cq = ln >> 4;           // col offset within 4-group
        const int dg = ln & 15;           // d float4-group
        const float4* Vg4 = (const float4*)(V + ((size_t)(b * L_SEQ + s0)) * D_HEAD);
        const float* arow0 = att + (2 * w) * W;
        const float* arow1 = arow0 + W;
        float4 acc0 = {0.f,0.f,0.f,0.f}, acc1 = {0.f,0.f,0.f,0.f};
        #pragma unroll 2
        for (int g = 0; g < WF4; ++g) {
            int col  = 4 * g + cq;
            int colc = (col < wcount) ? col : wcount - 1;     // att is 0 there
            float4 vv = Vg4[(size_t)colc * 16 + dg];          // 1 KB coalesced/wave
            float p0 = arow0[col];
            float p1 = arow1[col];
            acc0.x += p0 * vv.x; acc0.y += p0 * vv.y; acc0.z += p0 * vv.z; acc0.w += p0 * vv.w;
            acc1.x += p1 * vv.x; acc1.y += p1 * vv.y; acc1.z += p1 * vv.z; acc1.w += p1 * vv.w;
        }
        // reduce across cq (lane bits 4,5)
        #pragma unroll
        for (int off = 16; off <= 32; off <<= 1) {
            acc0.x += __shfl_xor(acc0.x, off); acc0.y += __shfl_xor(acc0.y, off);
            acc0.z += __shfl_xor(acc0.z, off); acc0.w += __shfl_xor(acc0.w, off);
            acc1.x += __shfl_xor(acc1.x, off); acc1.y += __shfl_xor(acc1.y, off);
            acc1.z += __shfl_xor(acc1.z, off); acc1.w += __shfl_xor(acc1.w, off);
        }
        if (ln < 16) {
            float4* o4 = (float4*)(OutO + ((size_t)(b * L_SEQ + q0 + 2 * w)) * D_HEAD);
            o4[dg]      = acc0;
            o4[16 + dg] = acc1;
        }
    }
}

extern "C" void kernel_launch(void* const* d_in, const int* in_sizes, int n_in,
                              void* d_out, int out_size, void* d_ws, size_t ws_size,
                              hipStream_t stream) {
    const float* Q = (const float*)d_in[0];
    const float* K = (const float*)d_in[1];
    const float* V = (const float*)d_in[2];
    float* OutO = (float*)d_out;
    float* OutA = OutO + (size_t)8 * L_SEQ * D_HEAD;   // attention follows out

    const int smem_bytes = (QB * W + QB * 68) * 4;     // 10624 B
    dim3 grid(8 * (L_SEQ / QB));    // 4096 blocks
    dim3 block(256);
    win_attn_kernel<<<grid, block, smem_bytes, stream>>>(Q, K, V, OutO, OutA);
}

// Round 4
// 239.071 us; speedup vs baseline: 2.7830x; 2.7830x over previous
//
#include <hip/hip_runtime.h>
#include <math.h>

#define L_SEQ 4096
#define D_HEAD 64
#define M_WIN 128
#define WIN 257              // 2*M+1
#define QB 8                 // query rows per block
#define W 264                // WIN + QB - 1, divisible by 8
#define WF4 66               // W/4
#define SCALE 0.125f         // 1/sqrt(64)

// LDS K tile: [264 rows][16 float4 slots], slot s holds global chunk
// c = s ^ ((row>>2)&15).  Staging writes: conflict-free (16 permuted slots
// per row). Phase-B reads (fixed c, 16 rows spaced 4 apart): slot index
// varies over all 16 values -> 32 banks covered, 2-way broadcast only.
__global__ __launch_bounds__(256, 2) void win_attn_kernel(
    const float* __restrict__ Q, const float* __restrict__ K,
    const float* __restrict__ V, float* __restrict__ OutO,
    float* __restrict__ OutA)
{
    extern __shared__ float smem[];
    float*  k_s  = smem;                   // 264*64 = 16896 floats (67584 B)
    float*  att  = smem + 264 * 64;        // [QB][W] = 2112 floats
    float*  q_s  = att + QB * W;           // [QB][68] padded = 544 floats
    float4* k_s4 = (float4*)k_s;
    float4* att4 = (float4*)att;
    float4* q_s4 = (float4*)q_s;

    const int t  = threadIdx.x;
    const int w  = t >> 6;                 // wave 0..3
    const int ln = t & 63;

    // XCD-bijective swizzle: 4096 blocks, 8 XCDs -> each XCD gets 512
    // consecutive logical blocks (= one batch) for K/V L2 locality.
    const int bid = (blockIdx.x & 7) * 512 + (blockIdx.x >> 3);
    const int b   = bid >> 9;              // batch
    const int q0  = (bid & 511) * QB;

    int s0 = q0 - M_WIN;
    if (s0 < 0) s0 = 0;
    if (s0 > L_SEQ - WIN) s0 = L_SEQ - WIN;
    const int wcount = (L_SEQ - s0 < W) ? (L_SEQ - s0) : W;   // valid union cols

    // ---------------- Phase A: stage Q (padded) + K (swizzled) --------------
    if (t < QB * 16) {
        const float4* Qg = (const float4*)(Q + ((size_t)(b * L_SEQ + q0)) * D_HEAD);
        q_s4[(t >> 4) * 17 + (t & 15)] = Qg[t];
    }
    {
        const float4* Kg = (const float4*)(K + ((size_t)(b * L_SEQ + s0)) * D_HEAD);
        const int c4 = t & 15;
        int row = t >> 4;                  // rows 0..255 over 16 iters
        #pragma unroll 4
        for (int it = 0; it < 16; ++it, row += 16) {
            int gr = (row < wcount) ? row : wcount - 1;   // clamp top edge
            float4 kk = Kg[(size_t)gr * 16 + c4];         // 1 KB coalesced/wave
            k_s4[row * 16 + (c4 ^ ((row >> 2) & 15))] = kk;
        }
        if (t < 128) {                     // tail rows 256..263
            int row2 = 256 + (t >> 4);
            int gr = (row2 < wcount) ? row2 : wcount - 1;
            float4 kk = Kg[(size_t)gr * 16 + c4];
            k_s4[row2 * 16 + (c4 ^ ((row2 >> 2) & 15))] = kk;
        }
    }
    __syncthreads();

    // ---------------- Phase B: scores, 2q x 4col register tile per lane -----
    {
        const int qg = ln >> 4;            // q rows {2qg, 2qg+1}
        const int cg = ln & 15;
        #pragma unroll 1
        for (int base = 64 * w; base < W; base += 256) {
            int col0 = base + 4 * cg;
            if (col0 < W) {
                int r4 = col0 >> 2;
                int m  = r4 & 15;          // swizzle mask for these 4 rows
                const float4* k0p = k_s4 + (size_t)(col0 + 0) * 16;
                const float4* k1p = k_s4 + (size_t)(col0 + 1) * 16;
                const float4* k2p = k_s4 + (size_t)(col0 + 2) * 16;
                const float4* k3p = k_s4 + (size_t)(col0 + 3) * 16;
                float4 a0 = {0.f,0.f,0.f,0.f};
                float4 a1 = {0.f,0.f,0.f,0.f};
                #pragma unroll
                for (int c = 0; c < 16; ++c) {
                    int sc = c ^ m;
                    float4 qa = q_s4[(2 * qg)     * 17 + c];
                    float4 qb = q_s4[(2 * qg + 1) * 17 + c];
                    float4 k0 = k0p[sc], k1 = k1p[sc], k2 = k2p[sc], k3 = k3p[sc];
                    a0.x += qa.x*k0.x + qa.y*k0.y + qa.z*k0.z + qa.w*k0.w;
                    a0.y += qa.x*k1.x + qa.y*k1.y + qa.z*k1.z + qa.w*k1.w;
                    a0.z += qa.x*k2.x + qa.y*k2.y + qa.z*k2.z + qa.w*k2.w;
                    a0.w += qa.x*k3.x + qa.y*k3.y + qa.z*k3.z + qa.w*k3.w;
                    a1.x += qb.x*k0.x + qb.y*k0.y + qb.z*k0.z + qb.w*k0.w;
                    a1.y += qb.x*k1.x + qb.y*k1.y + qb.z*k1.z + qb.w*k1.w;
                    a1.z += qb.x*k2.x + qb.y*k2.y + qb.z*k2.z + qb.w*k2.w;
                    a1.w += qb.x*k3.x + qb.y*k3.y + qb.z*k3.z + qb.w*k3.w;
                }
                float4 r0, r1;
                r0.x = a0.x*SCALE; r0.y = a0.y*SCALE; r0.z = a0.z*SCALE; r0.w = a0.w*SCALE;
                r1.x = a1.x*SCALE; r1.y = a1.y*SCALE; r1.z = a1.z*SCALE; r1.w = a1.w*SCALE;
                att4[(2 * qg)     * WF4 + r4] = r0;
                att4[(2 * qg + 1) * WF4 + r4] = r1;
            }
        }
    }
    __syncthreads();

    // ---------------- Phase C: masked softmax per q row (pre-normalized) ----
    {
        const int q  = t >> 5;             // 0..7
        const int i  = t & 31;
        const int qg = q0 + q;
        int st = qg - M_WIN;
        if (st < 0) st = 0;
        if (st > L_SEQ - WIN) st = L_SEQ - WIN;
        const int lo = st - s0;            // window start within union

        float sv[9];
        float m = -1e30f;
        #pragma unroll
        for (int j = 0; j < 9; ++j) {
            int col = i + 32 * j;
            float s = -1e30f;
            if (col < W) {
                s = att[q * W + col];
                if (col < lo || col >= lo + WIN) s = -1e30f;
            }
            sv[j] = s;
            m = fmaxf(m, s);
        }
        #pragma unroll
        for (int k = 16; k >= 1; k >>= 1) m = fmaxf(m, __shfl_xor(m, k, 32));
        float sum = 0.f;
        #pragma unroll
        for (int j = 0; j < 9; ++j) {
            float e = (sv[j] <= -1e29f) ? 0.f : __expf(sv[j] - m);
            sv[j] = e;
            sum += e;
        }
        #pragma unroll
        for (int k = 16; k >= 1; k >>= 1) sum += __shfl_xor(sum, k, 32);
        const float inv = 1.f / sum;
        #pragma unroll
        for (int j = 0; j < 9; ++j) {
            int col = i + 32 * j;
            if (col < W) att[q * W + col] = sv[j] * inv;   // exact 0 outside window
        }
    }
    __syncthreads();

    // ---------------- Phase E: PV first (small output); wave w -> rows 2w,2w+1
    {
        const int cq = ln >> 4;            // col offset within 4-group
        const int dg = ln & 15;            // d float4-group
        const float4* Vg4 = (const float4*)(V + ((size_t)(b * L_SEQ + s0)) * D_HEAD);
        const float* arow0 = att + (2 * w) * W;
        const float* arow1 = arow0 + W;
        float4 acc0 = {0.f,0.f,0.f,0.f}, acc1 = {0.f,0.f,0.f,0.f};
        #pragma unroll 2
        for (int g = 0; g < WF4; ++g) {
            int col  = 4 * g + cq;
            int colc = (col < wcount) ? col : wcount - 1;  // att is 0 there
            float4 vv = Vg4[(size_t)colc * 16 + dg];       // 1 KB coalesced/wave
            float p0 = arow0[col];
            float p1 = arow1[col];
            acc0.x += p0 * vv.x; acc0.y += p0 * vv.y; acc0.z += p0 * vv.z; acc0.w += p0 * vv.w;
            acc1.x += p1 * vv.x; acc1.y += p1 * vv.y; acc1.z += p1 * vv.z; acc1.w += p1 * vv.w;
        }
        #pragma unroll
        for (int off = 16; off <= 32; off <<= 1) {
            acc0.x += __shfl_xor(acc0.x, off); acc0.y += __shfl_xor(acc0.y, off);
            acc0.z += __shfl_xor(acc0.z, off); acc0.w += __shfl_xor(acc0.w, off);
            acc1.x += __shfl_xor(acc1.x, off); acc1.y += __shfl_xor(acc1.y, off);
            acc1.z += __shfl_xor(acc1.z, off); acc1.w += __shfl_xor(acc1.w, off);
        }
        if (ln < 16) {
            float4* o4 = (float4*)(OutO + ((size_t)(b * L_SEQ + q0 + 2 * w)) * D_HEAD);
            o4[dg]      = acc0;
            o4[16 + dg] = acc1;
        }
    }

    // ---------------- Phase D: stream dense attention rows (537 MB) ---------
    if ((s0 & 3) == 0) {
        #pragma unroll 1
        for (int ql = 0; ql < QB; ++ql) {
            float4* rowp = (float4*)(OutA + ((size_t)(b * L_SEQ + q0 + ql)) * L_SEQ);
            const float4* arow = (const float4*)(att + ql * W);
            #pragma unroll
            for (int jj = 0; jj < 4; ++jj) {
                int f4i = jj * 256 + t;
                int u   = 4 * f4i - s0;
                float4 wv = {0.f,0.f,0.f,0.f};
                if (u >= 0 && u < W) wv = arow[u >> 2];    // aligned b128 read
                rowp[f4i] = wv;                            // plain coalesced store
            }
        }
    } else {   // rare top-edge blocks (s0 = 3839)
        #pragma unroll 1
        for (int ql = 0; ql < QB; ++ql) {
            float4* rowp = (float4*)(OutA + ((size_t)(b * L_SEQ + q0 + ql)) * L_SEQ);
            const float* arow = att + ql * W;
            #pragma unroll
            for (int jj = 0; jj < 4; ++jj) {
                int f4i = jj * 256 + t;
                int u   = 4 * f4i - s0;
                float4 wv;
                wv.x = (u     >= 0 && u     < W) ? arow[u]     : 0.f;
                wv.y = (u + 1 >= 0 && u + 1 < W) ? arow[u + 1] : 0.f;
                wv.z = (u + 2 >= 0 && u + 2 < W) ? arow[u + 2] : 0.f;
                wv.w = (u + 3 >= 0 && u + 3 < W) ? arow[u + 3] : 0.f;
                rowp[f4i] = wv;
            }
        }
    }
}

extern "C" void kernel_launch(void* const* d_in, const int* in_sizes, int n_in,
                              void* d_out, int out_size, void* d_ws, size_t ws_size,
                              hipStream_t stream) {
    const float* Q = (const float*)d_in[0];
    const float* K = (const float*)d_in[1];
    const float* V = (const float*)d_in[2];
    float* OutO = (float*)d_out;
    float* OutA = OutO + (size_t)8 * L_SEQ * D_HEAD;   // attention follows out

    const int smem_bytes = (264 * 64 + QB * W + QB * 68) * 4;   // 78208 B
    hipFuncSetAttribute((const void*)win_attn_kernel,
                        hipFuncAttributeMaxDynamicSharedMemorySize, smem_bytes);

    dim3 grid(8 * (L_SEQ / QB));    // 4096 blocks
    dim3 block(256);
    win_attn_kernel<<<grid, block, smem_bytes, stream>>>(Q, K, V, OutO, OutA);
}